// Round 2
// baseline (1488.335 us; speedup 1.0000x reference)
//
#include <hip/hip_runtime.h>

#define B_ 1024
#define N_ 30
#define P_ 16
#define NR_ 870
#define DR_ 3
#define DE_ 5
#define DO_ 6
#define NT_ 5
#define TILE_ 32
#define NTILES_ ((NR_ + TILE_ - 1) / TILE_)   // 28

// ---------------------------------------------------------------------------
// K1: fused edge pipeline (fp32). Per block: one batch b, one tile of 32 edges.
//   aT[k][e] (k<16: Orr, 16..31: Ors, 32..34: RA) -> fr1 -> fr2 -> fr3 -> E
//   then Ebar[b][i][n] += sum_e E[e][i] * RR[b][n][e]  (atomic across tiles)
// fr1/fr2 weights are fp32 (double bf16 size), so the 128-wide fr2 K-dim is
// processed in two 64-halves, reusing one w1s/w2s LDS buffer with re-staging
// overlapped into the phase that doesn't read it.
// ---------------------------------------------------------------------------
__global__ __launch_bounds__(256) void k_edge(
    const float* __restrict__ x, const float* __restrict__ RR,
    const float* __restrict__ RS, const float* __restrict__ RA,
    const float* __restrict__ w1, const float* __restrict__ b1,
    const float* __restrict__ w2, const float* __restrict__ b2,
    const float* __restrict__ w3, const float* __restrict__ b3,
    float* __restrict__ Ebar)
{
    const int b   = blockIdx.y;
    const int r0  = blockIdx.x * TILE_;
    const int tid = threadIdx.x;

    __shared__ float w1s[35][68];            // [k][j_local] current half of fr1_w^T
    __shared__ float w2s[64][68];            // [j][k_local] current half of fr2_w
    __shared__ float b1s[128], b2s[64];
    __shared__ float xs[16][32];             // xs[p][n]
    __shared__ float rrs[30][33], rss[30][33];
    union UA { float aT[35][36]; float h2s[32][68]; };
    __shared__ UA u;
    __shared__ float h1s[32][68];            // current half of h1
    __shared__ float Ee[32][6];

    // ---- stage inputs + half-0 weights ----
    if (tid < 128) b1s[tid] = b1[tid];
    if (tid < 64)  b2s[tid] = b2[tid];
    for (int i = tid; i < N_ * P_; i += 256) {
        int n = i >> 4, p = i & 15;
        xs[p][n] = x[(b * N_ + n) * P_ + p];
    }
    for (int i = tid; i < N_ * TILE_; i += 256) {
        int n = i >> 5, e = i & 31;
        int r = r0 + e; if (r >= NR_) r = NR_ - 1;
        rrs[n][e] = RR[(b * N_ + n) * NR_ + r];
        rss[n][e] = RS[(b * N_ + n) * NR_ + r];
    }
    for (int i = tid; i < 64 * 35; i += 256) {   // w1s[k][jl] = fr1_w[jl][k]
        int jl = i / 35, k = i - jl * 35;
        w1s[k][jl] = w1[i];
    }
    for (int i = tid; i < 64 * 64; i += 256) {   // w2s[jl][kk] = fr2_w[jl][kk]
        int jl = i >> 6, kk = i & 63;
        w2s[jl][kk] = w2[jl * 128 + kk];
    }
    __syncthreads();

    // ---- phase A: aT[k][e] = marshalled edge inputs ----
    {
        int e = tid & 31, ph = tid >> 5;
        for (int p = ph; p < 16; p += 8) {
            float s1 = 0.f, s2 = 0.f;
            #pragma unroll
            for (int n = 0; n < N_; ++n) {
                float xv = xs[p][n];
                s1 += xv * rrs[n][e];
                s2 += xv * rss[n][e];
            }
            u.aT[p][e]      = s1;
            u.aT[16 + p][e] = s2;
        }
        if (tid < DR_ * TILE_) {
            int d = tid >> 5, e2 = tid & 31;
            int r = r0 + e2; if (r >= NR_) r = NR_ - 1;
            u.aT[32 + d][e2] = RA[(b * DR_ + d) * NR_ + r];
        }
    }
    __syncthreads();

    const int jt = (tid & 15) * 4;      // 0..60
    const int et = (tid >> 4) * 2;      // 0..30
    float acc2[2][4];
    #pragma unroll
    for (int a_ = 0; a_ < 2; ++a_)
        #pragma unroll
        for (int jj = 0; jj < 4; ++jj) acc2[a_][jj] = 0.f;

    #pragma unroll
    for (int h = 0; h < 2; ++h) {
        // ---- phase B: fr1 half h -> h1s[e][0..63] ----
        {
            float acc[2][4];
            #pragma unroll
            for (int ee = 0; ee < 2; ++ee)
                #pragma unroll
                for (int jj = 0; jj < 4; ++jj)
                    acc[ee][jj] = b1s[h * 64 + jt + jj];
            #pragma unroll
            for (int k = 0; k < 35; ++k) {
                float a0 = u.aT[k][et];
                float a1 = u.aT[k][et + 1];
                float4 wv = *(const float4*)&w1s[k][jt];
                acc[0][0] += a0 * wv.x; acc[0][1] += a0 * wv.y;
                acc[0][2] += a0 * wv.z; acc[0][3] += a0 * wv.w;
                acc[1][0] += a1 * wv.x; acc[1][1] += a1 * wv.y;
                acc[1][2] += a1 * wv.z; acc[1][3] += a1 * wv.w;
            }
            float4 s0, s1;
            s0.x = fmaxf(acc[0][0], 0.f); s0.y = fmaxf(acc[0][1], 0.f);
            s0.z = fmaxf(acc[0][2], 0.f); s0.w = fmaxf(acc[0][3], 0.f);
            s1.x = fmaxf(acc[1][0], 0.f); s1.y = fmaxf(acc[1][1], 0.f);
            s1.z = fmaxf(acc[1][2], 0.f); s1.w = fmaxf(acc[1][3], 0.f);
            *(float4*)&h1s[et][jt]     = s0;
            *(float4*)&h1s[et + 1][jt] = s1;
        }
        if (h == 1) {   // restage w2 half-1 (w2s last read in C(h=0), synced)
            for (int i = tid; i < 64 * 64; i += 256) {
                int jl = i >> 6, kk = i & 63;
                w2s[jl][kk] = w2[jl * 128 + 64 + kk];
            }
        }
        __syncthreads();

        // ---- phase C: fr2 partial accumulation over this half's 64 k's ----
        #pragma unroll 4
        for (int k = 0; k < 64; k += 4) {
            float4 h0  = *(const float4*)&h1s[et][k];
            float4 h1v = *(const float4*)&h1s[et + 1][k];
            #pragma unroll
            for (int jj = 0; jj < 4; ++jj) {
                float4 wv = *(const float4*)&w2s[jt + jj][k];
                acc2[0][jj] += h0.x * wv.x + h0.y * wv.y + h0.z * wv.z + h0.w * wv.w;
                acc2[1][jj] += h1v.x * wv.x + h1v.y * wv.y + h1v.z * wv.z + h1v.w * wv.w;
            }
        }
        if (h == 0) {   // restage w1 half-1 (w1s last read in B(h=0), synced)
            for (int i = tid; i < 64 * 35; i += 256) {
                int jl = i / 35, k = i - jl * 35;
                w1s[k][jl] = w1[64 * 35 + i];
            }
        }
        __syncthreads();
    }

    // ---- h2 = relu(acc2 + b2)  (aT dead: last read was B(h=1)) ----
    {
        float4 s0, s1;
        s0.x = fmaxf(acc2[0][0] + b2s[jt],     0.f);
        s0.y = fmaxf(acc2[0][1] + b2s[jt + 1], 0.f);
        s0.z = fmaxf(acc2[0][2] + b2s[jt + 2], 0.f);
        s0.w = fmaxf(acc2[0][3] + b2s[jt + 3], 0.f);
        s1.x = fmaxf(acc2[1][0] + b2s[jt],     0.f);
        s1.y = fmaxf(acc2[1][1] + b2s[jt + 1], 0.f);
        s1.z = fmaxf(acc2[1][2] + b2s[jt + 2], 0.f);
        s1.w = fmaxf(acc2[1][3] + b2s[jt + 3], 0.f);
        *(float4*)&u.h2s[et][jt]     = s0;
        *(float4*)&u.h2s[et + 1][jt] = s1;
    }
    __syncthreads();

    // ---- phase D1: fr3 (64 -> 5), w3/b3 from global (L1-hot) ----
    if (tid < TILE_ * DE_) {
        int e = tid / DE_, i = tid - e * DE_;
        float s = b3[i];
        const float* wr = w3 + i * 64;
        #pragma unroll
        for (int k = 0; k < 64; k += 4) {
            float4 wv = *(const float4*)&wr[k];
            float4 hv = *(const float4*)&u.h2s[e][k];
            s += hv.x * wv.x + hv.y * wv.y + hv.z * wv.z + hv.w * wv.w;
        }
        Ee[e][i] = ((r0 + e) < NR_) ? fmaxf(s, 0.f) : 0.f;
    }
    __syncthreads();

    // ---- phase D2: Ebar[b][i][n] += sum_e Ee[e][i] * rrs[n][e] ----
    if (tid < DE_ * N_) {
        int i = tid / N_, n = tid - i * N_;
        float s = 0.f;
        #pragma unroll
        for (int e = 0; e < TILE_; ++e) s += Ee[e][i] * rrs[n][e];
        atomicAdd(&Ebar[(b * DE_ + i) * N_ + n], s);
    }
}

// ---------------------------------------------------------------------------
// K2: node MLP per batch (fp32): C[n][21] -> fo1 -> fo2 -> fo3 -> f180[b][:]
// Same half-split structure as k_edge for the 128-wide fo2 K-dim.
// ---------------------------------------------------------------------------
__global__ __launch_bounds__(256) void k_node(
    const float* __restrict__ x, const float* __restrict__ Ebar,
    const float* __restrict__ wo1, const float* __restrict__ bo1,
    const float* __restrict__ wo2, const float* __restrict__ bo2,
    const float* __restrict__ wo3, const float* __restrict__ bo3,
    float* __restrict__ f180)
{
    const int b = blockIdx.x, tid = threadIdx.x;
    __shared__ float w1s[21][68];
    __shared__ float w2s[64][68];
    __shared__ float b1s[128], b2s[64];
    __shared__ float Cs[30][24];
    __shared__ float h1s[30][68];
    __shared__ float h2s[30][68];

    if (tid < 128) b1s[tid] = bo1[tid];
    if (tid < 64)  b2s[tid] = bo2[tid];
    for (int i = tid; i < 30 * 24; i += 256) {
        int n = i / 24, k = i - n * 24;
        float v = 0.f;
        if (k < 16)      v = x[(b * N_ + n) * P_ + k];
        else if (k < 21) v = Ebar[(b * DE_ + (k - 16)) * N_ + n];
        Cs[n][k] = v;
    }
    for (int i = tid; i < 64 * 21; i += 256) {   // w1s[k][jl] = fo1_w[jl][k]
        int jl = i / 21, k = i - jl * 21;
        w1s[k][jl] = wo1[i];
    }
    for (int i = tid; i < 64 * 64; i += 256) {   // w2s[jl][kk] = fo2_w[jl][kk]
        int jl = i >> 6, kk = i & 63;
        w2s[jl][kk] = wo2[jl * 128 + kk];
    }
    __syncthreads();

    const int jt = (tid & 15) * 4;      // 0..60
    const int ng = tid >> 4;            // 0..15 ; rows n = ng, ng+16
    float acc2[2][4];
    #pragma unroll
    for (int t = 0; t < 2; ++t)
        #pragma unroll
        for (int jj = 0; jj < 4; ++jj) acc2[t][jj] = 0.f;

    #pragma unroll
    for (int h = 0; h < 2; ++h) {
        // ---- fo1 half h -> h1s[n][0..63] ----
        #pragma unroll
        for (int t = 0; t < 2; ++t) {
            int n = ng + 16 * t;
            if (n < 30) {
                float acc[4] = { b1s[h * 64 + jt],     b1s[h * 64 + jt + 1],
                                 b1s[h * 64 + jt + 2], b1s[h * 64 + jt + 3] };
                #pragma unroll
                for (int k = 0; k < 21; ++k) {
                    float cv = Cs[n][k];
                    float4 wv = *(const float4*)&w1s[k][jt];
                    acc[0] += cv * wv.x; acc[1] += cv * wv.y;
                    acc[2] += cv * wv.z; acc[3] += cv * wv.w;
                }
                float4 st;
                st.x = fmaxf(acc[0], 0.f); st.y = fmaxf(acc[1], 0.f);
                st.z = fmaxf(acc[2], 0.f); st.w = fmaxf(acc[3], 0.f);
                *(float4*)&h1s[n][jt] = st;
            }
        }
        if (h == 1) {
            for (int i = tid; i < 64 * 64; i += 256) {
                int jl = i >> 6, kk = i & 63;
                w2s[jl][kk] = wo2[jl * 128 + 64 + kk];
            }
        }
        __syncthreads();

        // ---- fo2 partial over this half's 64 k's ----
        #pragma unroll
        for (int t = 0; t < 2; ++t) {
            int n = ng + 16 * t;
            if (n < 30) {
                #pragma unroll 4
                for (int k = 0; k < 64; k += 4) {
                    float4 hv = *(const float4*)&h1s[n][k];
                    #pragma unroll
                    for (int jj = 0; jj < 4; ++jj) {
                        float4 wv = *(const float4*)&w2s[jt + jj][k];
                        acc2[t][jj] += hv.x * wv.x + hv.y * wv.y
                                     + hv.z * wv.z + hv.w * wv.w;
                    }
                }
            }
        }
        if (h == 0) {
            for (int i = tid; i < 64 * 21; i += 256) {
                int jl = i / 21, k = i - jl * 21;
                w1s[k][jl] = wo1[64 * 21 + i];
            }
        }
        __syncthreads();
    }

    #pragma unroll
    for (int t = 0; t < 2; ++t) {
        int n = ng + 16 * t;
        if (n < 30) {
            float4 st;
            st.x = fmaxf(acc2[t][0] + b2s[jt],     0.f);
            st.y = fmaxf(acc2[t][1] + b2s[jt + 1], 0.f);
            st.z = fmaxf(acc2[t][2] + b2s[jt + 2], 0.f);
            st.w = fmaxf(acc2[t][3] + b2s[jt + 3], 0.f);
            *(float4*)&h2s[n][jt] = st;
        }
    }
    __syncthreads();

    // ---- fo3 (64 -> 6), weights from global ----
    if (tid < 180) {
        int n = tid / 6, i = tid - n * 6;
        float s = bo3[i];
        const float* wr = wo3 + i * 64;
        #pragma unroll
        for (int k = 0; k < 64; k += 4) {
            float4 wv = *(const float4*)&wr[k];
            float4 hv = *(const float4*)&h2s[n][k];
            s += hv.x * wv.x + hv.y * wv.y + hv.z * wv.z + hv.w * wv.w;
        }
        f180[b * 180 + tid] = fmaxf(s, 0.f);   // tid == n*6+i
    }
}

// ---------------------------------------------------------------------------
// K3: final MLP (fp32), 2 batches per block; weights streamed from global.
// ---------------------------------------------------------------------------
__global__ __launch_bounds__(256) void k_final(
    const float* __restrict__ f180,
    const float* __restrict__ wc1, const float* __restrict__ bc1,
    const float* __restrict__ wc2, const float* __restrict__ bc2,
    const float* __restrict__ wc3, const float* __restrict__ bc3,
    float* __restrict__ out)
{
    const int b0 = blockIdx.x * 2, tid = threadIdx.x;
    __shared__ float fs[2][184];
    __shared__ float h1s[2][128];
    __shared__ float h2s[2][64];

    for (int i = tid; i < 2 * 180; i += 256)
        fs[i / 180][i % 180] = f180[(b0 + i / 180) * 180 + (i % 180)];
    __syncthreads();

    {   // fc1: 2 x 128, dot-180
        int bl = tid >> 7, j = tid & 127;
        const float* wr = wc1 + j * 180;
        float s = bc1[j];
        #pragma unroll 5
        for (int k = 0; k < 180; k += 4) {
            float4 wv = *(const float4*)&wr[k];
            s += fs[bl][k] * wv.x + fs[bl][k + 1] * wv.y
               + fs[bl][k + 2] * wv.z + fs[bl][k + 3] * wv.w;
        }
        h1s[bl][j] = fmaxf(s, 0.f);
    }
    __syncthreads();

    if (tid < 128) {   // fc2: 2 x 64, dot-128
        int bl = tid >> 6, j = tid & 63;
        const float* wr = wc2 + j * 128;
        float s = bc2[j];
        #pragma unroll 4
        for (int k = 0; k < 128; k += 4) {
            float4 wv = *(const float4*)&wr[k];
            s += h1s[bl][k] * wv.x + h1s[bl][k + 1] * wv.y
               + h1s[bl][k + 2] * wv.z + h1s[bl][k + 3] * wv.w;
        }
        h2s[bl][j] = fmaxf(s, 0.f);
    }
    __syncthreads();

    if (tid < 10) {    // fc3: 2 x 5, dot-64
        int bl = tid / 5, t = tid - bl * 5;
        const float* wr = wc3 + t * 64;
        float s = bc3[t];
        #pragma unroll
        for (int k = 0; k < 64; k += 4) {
            float4 wv = *(const float4*)&wr[k];
            s += h2s[bl][k] * wv.x + h2s[bl][k + 1] * wv.y
               + h2s[bl][k + 2] * wv.z + h2s[bl][k + 3] * wv.w;
        }
        out[(b0 + bl) * NT_ + t] = s;
    }
}

extern "C" void kernel_launch(void* const* d_in, const int* in_sizes, int n_in,
                              void* d_out, int out_size, void* d_ws, size_t ws_size,
                              hipStream_t stream)
{
    const float* x    = (const float*)d_in[0];
    const float* RR   = (const float*)d_in[1];
    const float* RS   = (const float*)d_in[2];
    const float* RA   = (const float*)d_in[3];
    const float* fr1w = (const float*)d_in[4];
    const float* fr1b = (const float*)d_in[5];
    const float* fr2w = (const float*)d_in[6];
    const float* fr2b = (const float*)d_in[7];
    const float* fr3w = (const float*)d_in[8];
    const float* fr3b = (const float*)d_in[9];
    const float* fo1w = (const float*)d_in[10];
    const float* fo1b = (const float*)d_in[11];
    const float* fo2w = (const float*)d_in[12];
    const float* fo2b = (const float*)d_in[13];
    const float* fo3w = (const float*)d_in[14];
    const float* fo3b = (const float*)d_in[15];
    const float* fc1w = (const float*)d_in[16];
    const float* fc1b = (const float*)d_in[17];
    const float* fc2w = (const float*)d_in[18];
    const float* fc2b = (const float*)d_in[19];
    const float* fc3w = (const float*)d_in[20];
    const float* fc3b = (const float*)d_in[21];
    float* out = (float*)d_out;

    float* Ebar = (float*)d_ws;                    // B*5*30 floats
    float* f180 = Ebar + B_ * DE_ * N_;            // B*180 floats

    hipMemsetAsync(Ebar, 0, (size_t)B_ * DE_ * N_ * sizeof(float), stream);

    dim3 g1(NTILES_, B_);
    k_edge<<<g1, 256, 0, stream>>>(x, RR, RS, RA, fr1w, fr1b, fr2w, fr2b,
                                   fr3w, fr3b, Ebar);
    k_node<<<B_, 256, 0, stream>>>(x, Ebar, fo1w, fo1b, fo2w, fo2b,
                                   fo3w, fo3b, f180);
    k_final<<<B_ / 2, 256, 0, stream>>>(f180, fc1w, fc1b, fc2w, fc2b,
                                        fc3w, fc3b, out);
}

// Round 3
// 668.800 us; speedup vs baseline: 2.2254x; 2.2254x over previous
//
#include <hip/hip_runtime.h>

#define B_ 1024
#define N_ 30
#define P_ 16
#define NR_ 870
#define DR_ 3
#define DE_ 5
#define DO_ 6
#define NT_ 5

typedef unsigned short ushort_t;
typedef __attribute__((ext_vector_type(8))) short short8_t;
typedef __attribute__((ext_vector_type(4))) float f32x4;

union Frag { short8_t v; ushort_t u[8]; };

__device__ __forceinline__ float bf2f(ushort_t u) {
    union { unsigned int i; float f; } v; v.i = ((unsigned int)u) << 16; return v.f;
}
__device__ __forceinline__ ushort_t f2bf(float f) {
    union { float f; unsigned int i; } v; v.f = f;
    unsigned int x = v.i;
    return (ushort_t)((x + 0x7FFFu + ((x >> 16) & 1u)) >> 16);
}
__device__ __forceinline__ void split(float v, ushort_t& h, ushort_t& l) {
    h = f2bf(v);
    float r = v - bf2f(h);      // exact (Sterbenz)
    l = f2bf(r);
}
__device__ __forceinline__ f32x4 mfma(short8_t a, short8_t b, f32x4 c) {
    return __builtin_amdgcn_mfma_f32_16x16x32_bf16(a, b, c, 0, 0, 0);
}

// ---------------------------------------------------------------------------
// k_prep: pack weights & x into MFMA A-fragment layout (bf16 hi/lo split).
// A-frag layout (16x16x32): lane holds A[m = lane&15][k = (lane>>4)*8 + j].
// Frag f stored as [f][lane][j] ushorts -> one short8 load per lane.
// ---------------------------------------------------------------------------
__global__ __launch_bounds__(256) void k_prep(
    const float* __restrict__ x,  const float* __restrict__ w1,
    const float* __restrict__ w2, const float* __restrict__ wo1,
    const float* __restrict__ wo2,
    ushort_t* __restrict__ xAh,  ushort_t* __restrict__ xAl,
    ushort_t* __restrict__ w1h,  ushort_t* __restrict__ w1l,
    ushort_t* __restrict__ w2h,  ushort_t* __restrict__ w2l,
    ushort_t* __restrict__ wo1h, ushort_t* __restrict__ wo1l,
    ushort_t* __restrict__ wo2h, ushort_t* __restrict__ wo2l)
{
    const int blk = blockIdx.x, tid = threadIdx.x;
    if (blk < 1024) {                       // xA: A[m=p][k=n], per batch, 1 frag
        int b = blk;
        for (int idx = tid; idx < 512; idx += 256) {
            int lane = idx >> 3, j = idx & 7;
            int p = lane & 15, n = (lane >> 4) * 8 + j;
            float v = (n < N_) ? x[(b * N_ + n) * P_ + p] : 0.f;
            ushort_t h_, l_; split(v, h_, l_);
            xAh[b * 512 + idx] = h_; xAl[b * 512 + idx] = l_;
        }
    } else if (blk == 1024) {               // w1: 8 mt x 2 kt, A[m=j1][k], K pad 35->64
        for (int idx = tid; idx < 16 * 512; idx += 256) {
            int f = idx >> 9, eps = idx & 511;
            int lane = eps >> 3, j = eps & 7;
            int mt = f >> 1, kt = f & 1;
            int m = mt * 16 + (lane & 15);
            int k = kt * 32 + (lane >> 4) * 8 + j;
            float v = (k < 35) ? w1[m * 35 + k] : 0.f;
            ushort_t h_, l_; split(v, h_, l_);
            w1h[idx] = h_; w1l[idx] = l_;
        }
    } else if (blk == 1025) {               // w2: 4 mt x 4 kt, A[m=j2][k 0..127]
        for (int idx = tid; idx < 16 * 512; idx += 256) {
            int f = idx >> 9, eps = idx & 511;
            int lane = eps >> 3, j = eps & 7;
            int mt = f >> 2, kt = f & 3;
            int m = mt * 16 + (lane & 15);
            int k = kt * 32 + (lane >> 4) * 8 + j;
            float v = w2[m * 128 + k];
            ushort_t h_, l_; split(v, h_, l_);
            w2h[idx] = h_; w2l[idx] = l_;
        }
    } else if (blk == 1026) {               // wo1: 8 mt x 1 kt, K pad 21->32
        for (int idx = tid; idx < 8 * 512; idx += 256) {
            int f = idx >> 9, eps = idx & 511;
            int lane = eps >> 3, j = eps & 7;
            int m = f * 16 + (lane & 15);
            int k = (lane >> 4) * 8 + j;
            float v = (k < 21) ? wo1[m * 21 + k] : 0.f;
            ushort_t h_, l_; split(v, h_, l_);
            wo1h[idx] = h_; wo1l[idx] = l_;
        }
    } else {                                // wo2: 4 mt x 4 kt
        for (int idx = tid; idx < 16 * 512; idx += 256) {
            int f = idx >> 9, eps = idx & 511;
            int lane = eps >> 3, j = eps & 7;
            int mt = f >> 2, kt = f & 3;
            int m = mt * 16 + (lane & 15);
            int k = kt * 32 + (lane >> 4) * 8 + j;
            float v = wo2[m * 128 + k];
            ushort_t h_, l_; split(v, h_, l_);
            wo2h[idx] = h_; wo2l[idx] = l_;
        }
    }
}

// ---------------------------------------------------------------------------
// k_edge: MFMA edge pipeline. Block = (batch b, 64-edge tile).
// Orientation D = W @ actT: cols = edges -> C-layout rows are 4 consecutive
// k's of the next layer's B operand (pack-4 contiguous LDS writes).
// 3-term bf16 split per GEMM: Wh@ah + Wl@ah + Wh@al (rel err ~2^-18).
// ---------------------------------------------------------------------------
__global__ __launch_bounds__(256) void k_edge(
    const float* __restrict__ RR, const float* __restrict__ RS,
    const float* __restrict__ RA,
    const float* __restrict__ b1, const float* __restrict__ b2,
    const float* __restrict__ w3, const float* __restrict__ b3,
    const ushort_t* __restrict__ xAh, const ushort_t* __restrict__ xAl,
    const ushort_t* __restrict__ w1h, const ushort_t* __restrict__ w1l,
    const ushort_t* __restrict__ w2h, const ushort_t* __restrict__ w2l,
    float* __restrict__ Ebar)
{
    const int b   = blockIdx.y;
    const int r0  = blockIdx.x * 64;
    const int tid = threadIdx.x;
    const int lane = tid & 63;
    const int wv   = tid >> 6;          // wave 0..3
    const int l15  = lane & 15;
    const int q    = lane >> 4;         // quad 0..3

    // aT: [hi/lo][64 e][72 k]  (stride 144 B: bank +4/row -> 2-way max; 16B-aligned)
    // h2T aliases aT (aT dead after fr1 B-reads, h2T written after sync #3)
    __shared__ union {
        ushort_t aT[2][64][72];
        float    h2T[64][68];           // stride 272 B
    } ua;
    __shared__ ushort_t h1T[2][64][136];   // stride 272 B
    __shared__ float rrs[30][66];
    __shared__ float Ee[64][6];
    __shared__ float b1s[128], b2s[64];

    if (tid < 128) b1s[tid] = b1[tid];
    if (tid < 64)  b2s[tid] = b2[tid];

    // ---- phase A: Orr/Ors via MFMA; wave wv owns e-tile wv ----
    const int eloc = wv * 16 + l15;
    const int r = r0 + eloc;
    const bool rvalid = (r < NR_);

    Frag xh, xl;
    xh.v = ((const short8_t*)xAh)[b * 64 + lane];
    xl.v = ((const short8_t*)xAl)[b * 64 + lane];

    Frag rrh, rrl, rsh, rsl;
    #pragma unroll
    for (int j = 0; j < 8; ++j) {
        int n = q * 8 + j;
        float vr = 0.f, vs = 0.f;
        if (n < N_ && rvalid) {
            vr = RR[(b * N_ + n) * NR_ + r];
            vs = RS[(b * N_ + n) * NR_ + r];
        }
        ushort_t h_, l_;
        split(vr, h_, l_); rrh.u[j] = h_; rrl.u[j] = l_;
        split(vs, h_, l_); rsh.u[j] = h_; rsl.u[j] = l_;
        if (n < N_) rrs[n][eloc] = vr;
    }

    f32x4 aR = {0.f, 0.f, 0.f, 0.f}, aS = {0.f, 0.f, 0.f, 0.f};
    aR = mfma(xh.v, rrh.v, aR); aR = mfma(xl.v, rrh.v, aR); aR = mfma(xh.v, rrl.v, aR);
    aS = mfma(xh.v, rsh.v, aS); aS = mfma(xl.v, rsh.v, aS); aS = mfma(xh.v, rsl.v, aS);

    // zero aT k=32..63 (16 B per lane, wave-local rows)
    {
        uint4 z = {0u, 0u, 0u, 0u};
        *(uint4*)&ua.aT[0][eloc][32 + q * 8] = z;
        *(uint4*)&ua.aT[1][eloc][32 + q * 8] = z;
    }
    // write Orr at k=q*4..q*4+3, Ors at 16+q*4.. (pack 4, 8B-aligned)
    {
        ushort4 ph, pl;
        ushort_t h_, l_;
        split(aR[0], h_, l_); ph.x = h_; pl.x = l_;
        split(aR[1], h_, l_); ph.y = h_; pl.y = l_;
        split(aR[2], h_, l_); ph.z = h_; pl.z = l_;
        split(aR[3], h_, l_); ph.w = h_; pl.w = l_;
        *(ushort4*)&ua.aT[0][eloc][q * 4] = ph;
        *(ushort4*)&ua.aT[1][eloc][q * 4] = pl;
        split(aS[0], h_, l_); ph.x = h_; pl.x = l_;
        split(aS[1], h_, l_); ph.y = h_; pl.y = l_;
        split(aS[2], h_, l_); ph.z = h_; pl.z = l_;
        split(aS[3], h_, l_); ph.w = h_; pl.w = l_;
        *(ushort4*)&ua.aT[0][eloc][16 + q * 4] = ph;
        *(ushort4*)&ua.aT[1][eloc][16 + q * 4] = pl;
    }
    // RA at k=32..34 (after the zero in program order; wave-local rows)
    if (q < DR_) {
        float v = rvalid ? RA[(b * DR_ + q) * NR_ + r] : 0.f;
        ushort_t h_, l_; split(v, h_, l_);
        ua.aT[0][eloc][32 + q] = h_;
        ua.aT[1][eloc][32 + q] = l_;
    }
    __syncthreads();

    // ---- fr1: D1[j1][e] = W1 @ aT^T; wave owns mt = {wv, wv+4} ----
    {
        short8_t W1hf[2][2], W1lf[2][2];
        #pragma unroll
        for (int mi = 0; mi < 2; ++mi) {
            int mt = wv + mi * 4;
            #pragma unroll
            for (int kt = 0; kt < 2; ++kt) {
                W1hf[mi][kt] = ((const short8_t*)w1h)[(mt * 2 + kt) * 64 + lane];
                W1lf[mi][kt] = ((const short8_t*)w1l)[(mt * 2 + kt) * 64 + lane];
            }
        }
        #pragma unroll
        for (int et = 0; et < 4; ++et) {
            int e = et * 16 + l15;
            short8_t Bh[2], Bl[2];
            #pragma unroll
            for (int kt = 0; kt < 2; ++kt) {
                Bh[kt] = *(const short8_t*)&ua.aT[0][e][kt * 32 + q * 8];
                Bl[kt] = *(const short8_t*)&ua.aT[1][e][kt * 32 + q * 8];
            }
            #pragma unroll
            for (int mi = 0; mi < 2; ++mi) {
                int mt = wv + mi * 4;
                f32x4 acc = {0.f, 0.f, 0.f, 0.f};
                #pragma unroll
                for (int kt = 0; kt < 2; ++kt) {
                    acc = mfma(W1hf[mi][kt], Bh[kt], acc);
                    acc = mfma(W1lf[mi][kt], Bh[kt], acc);
                    acc = mfma(W1hf[mi][kt], Bl[kt], acc);
                }
                ushort4 ph, pl; ushort_t h_, l_;
                float hv;
                hv = fmaxf(acc[0] + b1s[mt * 16 + q * 4 + 0], 0.f); split(hv, h_, l_); ph.x = h_; pl.x = l_;
                hv = fmaxf(acc[1] + b1s[mt * 16 + q * 4 + 1], 0.f); split(hv, h_, l_); ph.y = h_; pl.y = l_;
                hv = fmaxf(acc[2] + b1s[mt * 16 + q * 4 + 2], 0.f); split(hv, h_, l_); ph.z = h_; pl.z = l_;
                hv = fmaxf(acc[3] + b1s[mt * 16 + q * 4 + 3], 0.f); split(hv, h_, l_); ph.w = h_; pl.w = l_;
                *(ushort4*)&h1T[0][e][mt * 16 + q * 4] = ph;
                *(ushort4*)&h1T[1][e][mt * 16 + q * 4] = pl;
            }
        }
    }
    __syncthreads();

    // ---- fr2: D2[j2][e] = W2 @ h1^T; wave owns mt = wv ----
    {
        short8_t W2hf[4], W2lf[4];
        #pragma unroll
        for (int kt = 0; kt < 4; ++kt) {
            W2hf[kt] = ((const short8_t*)w2h)[(wv * 4 + kt) * 64 + lane];
            W2lf[kt] = ((const short8_t*)w2l)[(wv * 4 + kt) * 64 + lane];
        }
        #pragma unroll
        for (int et = 0; et < 4; ++et) {
            int e = et * 16 + l15;
            f32x4 acc = {0.f, 0.f, 0.f, 0.f};
            #pragma unroll
            for (int kt = 0; kt < 4; ++kt) {
                short8_t bh = *(const short8_t*)&h1T[0][e][kt * 32 + q * 8];
                short8_t bl = *(const short8_t*)&h1T[1][e][kt * 32 + q * 8];
                acc = mfma(W2hf[kt], bh, acc);
                acc = mfma(W2lf[kt], bh, acc);
                acc = mfma(W2hf[kt], bl, acc);
            }
            float4 st;
            st.x = fmaxf(acc[0] + b2s[wv * 16 + q * 4 + 0], 0.f);
            st.y = fmaxf(acc[1] + b2s[wv * 16 + q * 4 + 1], 0.f);
            st.z = fmaxf(acc[2] + b2s[wv * 16 + q * 4 + 2], 0.f);
            st.w = fmaxf(acc[3] + b2s[wv * 16 + q * 4 + 3], 0.f);
            *(float4*)&ua.h2T[e][wv * 16 + q * 4] = st;
        }
    }
    __syncthreads();

    // ---- fr3 (64 -> 5), VALU; w3/b3 from global (L2-hot) ----
    for (int it = tid; it < 64 * DE_; it += 256) {
        int e = it / DE_, i = it - e * DE_;
        float s = b3[i];
        const float* wr = w3 + i * 64;
        #pragma unroll
        for (int k = 0; k < 64; k += 4) {
            float4 hv = *(const float4*)&ua.h2T[e][k];
            float4 wv4 = *(const float4*)&wr[k];
            s += hv.x * wv4.x + hv.y * wv4.y + hv.z * wv4.z + hv.w * wv4.w;
        }
        Ee[e][i] = ((r0 + e) < NR_) ? fmaxf(s, 0.f) : 0.f;
    }
    __syncthreads();

    // ---- Ebar[b][i][n] += sum_e Ee[e][i] * rrs[n][e] ----
    if (tid < DE_ * N_) {
        int i = tid / N_, n = tid - i * N_;
        float s = 0.f;
        #pragma unroll
        for (int e = 0; e < 64; ++e) s += Ee[e][i] * rrs[n][e];
        atomicAdd(&Ebar[(b * DE_ + i) * N_ + n], s);
    }
}

// ---------------------------------------------------------------------------
// k_node: MFMA node MLP. Block = 2 batches, cols = 64 (2 x 32-slot, n<30 valid).
// ---------------------------------------------------------------------------
__global__ __launch_bounds__(256) void k_node(
    const float* __restrict__ x, const float* __restrict__ Ebar,
    const float* __restrict__ bo1, const float* __restrict__ bo2,
    const float* __restrict__ wo3, const float* __restrict__ bo3,
    const ushort_t* __restrict__ wo1h, const ushort_t* __restrict__ wo1l,
    const ushort_t* __restrict__ wo2h, const ushort_t* __restrict__ wo2l,
    float* __restrict__ f180)
{
    const int b0 = blockIdx.x * 2;
    const int tid = threadIdx.x;
    const int lane = tid & 63;
    const int wv = tid >> 6;
    const int l15 = lane & 15;
    const int q = lane >> 4;

    __shared__ ushort_t cT[2][64][40];        // stride 80 B, 16B-aligned reads
    __shared__ ushort_t h1T[2][64][136];
    __shared__ float h2T[64][68];
    __shared__ float b1s[128], b2s[64];

    if (tid < 128) b1s[tid] = bo1[tid];
    if (tid < 64)  b2s[tid] = bo2[tid];

    for (int idx = tid; idx < 64 * 32; idx += 256) {
        int c = idx >> 5, k = idx & 31;
        int bb = c >> 5, n = c & 31;
        float v = 0.f;
        if (n < N_) {
            if (k < 16)      v = x[((b0 + bb) * N_ + n) * P_ + k];
            else if (k < 21) v = Ebar[((b0 + bb) * DE_ + (k - 16)) * N_ + n];
        }
        ushort_t h_, l_; split(v, h_, l_);
        cT[0][c][k] = h_; cT[1][c][k] = l_;
    }
    __syncthreads();

    // ---- fo1: D[j][c] = Wo1 @ C^T; wave owns mt = {wv, wv+4}; K = 1 tile ----
    {
        short8_t Wh[2], Wl[2];
        #pragma unroll
        for (int mi = 0; mi < 2; ++mi) {
            int mt = wv + mi * 4;
            Wh[mi] = ((const short8_t*)wo1h)[mt * 64 + lane];
            Wl[mi] = ((const short8_t*)wo1l)[mt * 64 + lane];
        }
        #pragma unroll
        for (int et = 0; et < 4; ++et) {
            int c = et * 16 + l15;
            short8_t bh = *(const short8_t*)&cT[0][c][q * 8];
            short8_t bl = *(const short8_t*)&cT[1][c][q * 8];
            #pragma unroll
            for (int mi = 0; mi < 2; ++mi) {
                int mt = wv + mi * 4;
                f32x4 acc = {0.f, 0.f, 0.f, 0.f};
                acc = mfma(Wh[mi], bh, acc);
                acc = mfma(Wl[mi], bh, acc);
                acc = mfma(Wh[mi], bl, acc);
                ushort4 ph, pl; ushort_t h_, l_; float hv;
                hv = fmaxf(acc[0] + b1s[mt * 16 + q * 4 + 0], 0.f); split(hv, h_, l_); ph.x = h_; pl.x = l_;
                hv = fmaxf(acc[1] + b1s[mt * 16 + q * 4 + 1], 0.f); split(hv, h_, l_); ph.y = h_; pl.y = l_;
                hv = fmaxf(acc[2] + b1s[mt * 16 + q * 4 + 2], 0.f); split(hv, h_, l_); ph.z = h_; pl.z = l_;
                hv = fmaxf(acc[3] + b1s[mt * 16 + q * 4 + 3], 0.f); split(hv, h_, l_); ph.w = h_; pl.w = l_;
                *(ushort4*)&h1T[0][c][mt * 16 + q * 4] = ph;
                *(ushort4*)&h1T[1][c][mt * 16 + q * 4] = pl;
            }
        }
    }
    __syncthreads();

    // ---- fo2: wave owns mt = wv ----
    {
        short8_t Wh[4], Wl[4];
        #pragma unroll
        for (int kt = 0; kt < 4; ++kt) {
            Wh[kt] = ((const short8_t*)wo2h)[(wv * 4 + kt) * 64 + lane];
            Wl[kt] = ((const short8_t*)wo2l)[(wv * 4 + kt) * 64 + lane];
        }
        #pragma unroll
        for (int et = 0; et < 4; ++et) {
            int c = et * 16 + l15;
            f32x4 acc = {0.f, 0.f, 0.f, 0.f};
            #pragma unroll
            for (int kt = 0; kt < 4; ++kt) {
                short8_t bh = *(const short8_t*)&h1T[0][c][kt * 32 + q * 8];
                short8_t bl = *(const short8_t*)&h1T[1][c][kt * 32 + q * 8];
                acc = mfma(Wh[kt], bh, acc);
                acc = mfma(Wl[kt], bh, acc);
                acc = mfma(Wh[kt], bl, acc);
            }
            float4 st;
            st.x = fmaxf(acc[0] + b2s[wv * 16 + q * 4 + 0], 0.f);
            st.y = fmaxf(acc[1] + b2s[wv * 16 + q * 4 + 1], 0.f);
            st.z = fmaxf(acc[2] + b2s[wv * 16 + q * 4 + 2], 0.f);
            st.w = fmaxf(acc[3] + b2s[wv * 16 + q * 4 + 3], 0.f);
            *(float4*)&h2T[c][wv * 16 + q * 4] = st;
        }
    }
    __syncthreads();

    // ---- fo3 (64 -> 6) + store f180 ----
    for (int it = tid; it < 384; it += 256) {
        int c = it / DO_, i = it - c * DO_;
        if (c < 64) {
            int bb = c >> 5, n = c & 31;
            if (n < N_) {
                float s = bo3[i];
                const float* wr = wo3 + i * 64;
                #pragma unroll
                for (int k = 0; k < 64; k += 4) {
                    float4 hv = *(const float4*)&h2T[c][k];
                    float4 wv4 = *(const float4*)&wr[k];
                    s += hv.x * wv4.x + hv.y * wv4.y + hv.z * wv4.z + hv.w * wv4.w;
                }
                f180[(b0 + bb) * 180 + n * DO_ + i] = fmaxf(s, 0.f);
            }
        }
    }
}

// ---------------------------------------------------------------------------
// k_final: fp32 VALU (tiny), 2 batches/block.
// ---------------------------------------------------------------------------
__global__ __launch_bounds__(256) void k_final(
    const float* __restrict__ f180,
    const float* __restrict__ wc1, const float* __restrict__ bc1,
    const float* __restrict__ wc2, const float* __restrict__ bc2,
    const float* __restrict__ wc3, const float* __restrict__ bc3,
    float* __restrict__ out)
{
    const int b0 = blockIdx.x * 2, tid = threadIdx.x;
    __shared__ float fs[2][184];
    __shared__ float h1s[2][128];
    __shared__ float h2s[2][64];

    for (int i = tid; i < 2 * 180; i += 256)
        fs[i / 180][i % 180] = f180[(b0 + i / 180) * 180 + (i % 180)];
    __syncthreads();

    {
        int bl = tid >> 7, j = tid & 127;
        const float* wr = wc1 + j * 180;
        float s = bc1[j];
        #pragma unroll 5
        for (int k = 0; k < 180; k += 4) {
            float4 wv = *(const float4*)&wr[k];
            s += fs[bl][k] * wv.x + fs[bl][k + 1] * wv.y
               + fs[bl][k + 2] * wv.z + fs[bl][k + 3] * wv.w;
        }
        h1s[bl][j] = fmaxf(s, 0.f);
    }
    __syncthreads();

    if (tid < 128) {
        int bl = tid >> 6, j = tid & 63;
        const float* wr = wc2 + j * 128;
        float s = bc2[j];
        #pragma unroll 4
        for (int k = 0; k < 128; k += 4) {
            float4 wv = *(const float4*)&wr[k];
            s += h1s[bl][k] * wv.x + h1s[bl][k + 1] * wv.y
               + h1s[bl][k + 2] * wv.z + h1s[bl][k + 3] * wv.w;
        }
        h2s[bl][j] = fmaxf(s, 0.f);
    }
    __syncthreads();

    if (tid < 10) {
        int bl = tid / 5, t = tid - bl * 5;
        const float* wr = wc3 + t * 64;
        float s = bc3[t];
        #pragma unroll
        for (int k = 0; k < 64; k += 4) {
            float4 wv = *(const float4*)&wr[k];
            s += h2s[bl][k] * wv.x + h2s[bl][k + 1] * wv.y
               + h2s[bl][k + 2] * wv.z + h2s[bl][k + 3] * wv.w;
        }
        out[(b0 + bl) * NT_ + t] = s;
    }
}

extern "C" void kernel_launch(void* const* d_in, const int* in_sizes, int n_in,
                              void* d_out, int out_size, void* d_ws, size_t ws_size,
                              hipStream_t stream)
{
    const float* x    = (const float*)d_in[0];
    const float* RR   = (const float*)d_in[1];
    const float* RS   = (const float*)d_in[2];
    const float* RA   = (const float*)d_in[3];
    const float* fr1w = (const float*)d_in[4];
    const float* fr1b = (const float*)d_in[5];
    const float* fr2w = (const float*)d_in[6];
    const float* fr2b = (const float*)d_in[7];
    const float* fr3w = (const float*)d_in[8];
    const float* fr3b = (const float*)d_in[9];
    const float* fo1w = (const float*)d_in[10];
    const float* fo1b = (const float*)d_in[11];
    const float* fo2w = (const float*)d_in[12];
    const float* fo2b = (const float*)d_in[13];
    const float* fo3w = (const float*)d_in[14];
    const float* fo3b = (const float*)d_in[15];
    const float* fc1w = (const float*)d_in[16];
    const float* fc1b = (const float*)d_in[17];
    const float* fc2w = (const float*)d_in[18];
    const float* fc2b = (const float*)d_in[19];
    const float* fc3w = (const float*)d_in[20];
    const float* fc3b = (const float*)d_in[21];
    float* out = (float*)d_out;

    // ---- workspace map ----
    float* Ebar = (float*)d_ws;                       // 1024*5*30
    float* f180 = Ebar + B_ * DE_ * N_;               // 1024*180
    ushort_t* base = (ushort_t*)(f180 + B_ * 180);
    ushort_t* xAh  = base;             ushort_t* xAl  = xAh  + 1024 * 512;
    ushort_t* w1h  = xAl  + 1024*512;  ushort_t* w1l  = w1h  + 16 * 512;
    ushort_t* w2h  = w1l  + 16*512;    ushort_t* w2l  = w2h  + 16 * 512;
    ushort_t* wo1h = w2l  + 16*512;    ushort_t* wo1l = wo1h + 8 * 512;
    ushort_t* wo2h = wo1l + 8*512;     ushort_t* wo2l = wo2h + 16 * 512;

    hipMemsetAsync(Ebar, 0, (size_t)B_ * DE_ * N_ * sizeof(float), stream);

    k_prep<<<1028, 256, 0, stream>>>(x, fr1w, fr2w, fo1w, fo2w,
                                     xAh, xAl, w1h, w1l, w2h, w2l,
                                     wo1h, wo1l, wo2h, wo2l);

    dim3 g1(14, B_);   // 14 * 64 = 896 >= 870 edges
    k_edge<<<g1, 256, 0, stream>>>(RR, RS, RA, fr1b, fr2b, fr3w, fr3b,
                                   xAh, xAl, w1h, w1l, w2h, w2l, Ebar);
    k_node<<<B_ / 2, 256, 0, stream>>>(x, Ebar, fo1b, fo2b, fo3w, fo3b,
                                       wo1h, wo1l, wo2h, wo2l, f180);
    k_final<<<B_ / 2, 256, 0, stream>>>(f180, fc1w, fc1b, fc2w, fc2b,
                                        fc3w, fc3b, out);
}

// Round 4
// 633.814 us; speedup vs baseline: 2.3482x; 1.0552x over previous
//
#include <hip/hip_runtime.h>

#define B_ 1024
#define N_ 30
#define P_ 16
#define NR_ 870
#define DR_ 3
#define DE_ 5
#define DO_ 6
#define NT_ 5

typedef unsigned short ushort_t;
typedef __attribute__((ext_vector_type(8))) short short8_t;
typedef __attribute__((ext_vector_type(4))) float f32x4;

union Frag { short8_t v; ushort_t u[8]; };

__device__ __forceinline__ float bf2f(ushort_t u) {
    union { unsigned int i; float f; } v; v.i = ((unsigned int)u) << 16; return v.f;
}
__device__ __forceinline__ ushort_t f2bf(float f) {
    union { float f; unsigned int i; } v; v.f = f;
    unsigned int x = v.i;
    return (ushort_t)((x + 0x7FFFu + ((x >> 16) & 1u)) >> 16);
}
__device__ __forceinline__ void split(float v, ushort_t& h, ushort_t& l) {
    h = f2bf(v);
    float r = v - bf2f(h);      // exact (Sterbenz)
    l = f2bf(r);
}
__device__ __forceinline__ f32x4 mfma(short8_t a, short8_t b, f32x4 c) {
    return __builtin_amdgcn_mfma_f32_16x16x32_bf16(a, b, c, 0, 0, 0);
}

// ---------------------------------------------------------------------------
// k_prep: pack weights & x into MFMA A-fragment layout (bf16 hi/lo split).
// A-frag layout (16x16x32): lane holds A[m = lane&15][k = (lane>>4)*8 + j].
// ---------------------------------------------------------------------------
__global__ __launch_bounds__(256) void k_prep(
    const float* __restrict__ x,  const float* __restrict__ w1,
    const float* __restrict__ w2, const float* __restrict__ wo1,
    const float* __restrict__ wo2,
    ushort_t* __restrict__ xAh,  ushort_t* __restrict__ xAl,
    ushort_t* __restrict__ w1h,  ushort_t* __restrict__ w1l,
    ushort_t* __restrict__ w2h,  ushort_t* __restrict__ w2l,
    ushort_t* __restrict__ wo1h, ushort_t* __restrict__ wo1l,
    ushort_t* __restrict__ wo2h, ushort_t* __restrict__ wo2l)
{
    const int blk = blockIdx.x, tid = threadIdx.x;
    if (blk < 1024) {                       // xA: A[m=p][k=n], per batch, 1 frag
        int b = blk;
        for (int idx = tid; idx < 512; idx += 256) {
            int lane = idx >> 3, j = idx & 7;
            int p = lane & 15, n = (lane >> 4) * 8 + j;
            float v = (n < N_) ? x[(b * N_ + n) * P_ + p] : 0.f;
            ushort_t h_, l_; split(v, h_, l_);
            xAh[b * 512 + idx] = h_; xAl[b * 512 + idx] = l_;
        }
    } else if (blk == 1024) {               // w1: 8 mt x 2 kt, K pad 35->64
        for (int idx = tid; idx < 16 * 512; idx += 256) {
            int f = idx >> 9, eps = idx & 511;
            int lane = eps >> 3, j = eps & 7;
            int mt = f >> 1, kt = f & 1;
            int m = mt * 16 + (lane & 15);
            int k = kt * 32 + (lane >> 4) * 8 + j;
            float v = (k < 35) ? w1[m * 35 + k] : 0.f;
            ushort_t h_, l_; split(v, h_, l_);
            w1h[idx] = h_; w1l[idx] = l_;
        }
    } else if (blk == 1025) {               // w2: 4 mt x 4 kt
        for (int idx = tid; idx < 16 * 512; idx += 256) {
            int f = idx >> 9, eps = idx & 511;
            int lane = eps >> 3, j = eps & 7;
            int mt = f >> 2, kt = f & 3;
            int m = mt * 16 + (lane & 15);
            int k = kt * 32 + (lane >> 4) * 8 + j;
            float v = w2[m * 128 + k];
            ushort_t h_, l_; split(v, h_, l_);
            w2h[idx] = h_; w2l[idx] = l_;
        }
    } else if (blk == 1026) {               // wo1: 8 mt x 1 kt, K pad 21->32
        for (int idx = tid; idx < 8 * 512; idx += 256) {
            int f = idx >> 9, eps = idx & 511;
            int lane = eps >> 3, j = eps & 7;
            int m = f * 16 + (lane & 15);
            int k = (lane >> 4) * 8 + j;
            float v = (k < 21) ? wo1[m * 21 + k] : 0.f;
            ushort_t h_, l_; split(v, h_, l_);
            wo1h[idx] = h_; wo1l[idx] = l_;
        }
    } else {                                // wo2: 4 mt x 4 kt
        for (int idx = tid; idx < 16 * 512; idx += 256) {
            int f = idx >> 9, eps = idx & 511;
            int lane = eps >> 3, j = eps & 7;
            int mt = f >> 2, kt = f & 3;
            int m = mt * 16 + (lane & 15);
            int k = kt * 32 + (lane >> 4) * 8 + j;
            float v = wo2[m * 128 + k];
            ushort_t h_, l_; split(v, h_, l_);
            wo2h[idx] = h_; wo2l[idx] = l_;
        }
    }
}

// ---------------------------------------------------------------------------
// k_edge v3: MFMA edge pipeline, 64 edges/block, LDS 46.5 KB -> 3 blocks/CU.
//  - RR/RS staged coalesced (float2) into LDS, frags built from LDS
//  - fr1 in two 64-output halves; fr2 accumulates partials in registers
//  - rsStage aliases h1T; h2T aliases aT (liveness: see barrier schedule)
// ---------------------------------------------------------------------------
__global__ __launch_bounds__(256) void k_edge(
    const float* __restrict__ RR, const float* __restrict__ RS,
    const float* __restrict__ RA,
    const float* __restrict__ b1, const float* __restrict__ b2,
    const float* __restrict__ w3, const float* __restrict__ b3,
    const ushort_t* __restrict__ xAh, const ushort_t* __restrict__ xAl,
    const ushort_t* __restrict__ w1h, const ushort_t* __restrict__ w1l,
    const ushort_t* __restrict__ w2h, const ushort_t* __restrict__ w2l,
    float* __restrict__ Ebar)
{
    const int b   = blockIdx.y;
    const int r0  = blockIdx.x * 64;
    const int tid = threadIdx.x;
    const int lane = tid & 63;
    const int wv   = tid >> 6;          // wave 0..3
    const int l15  = lane & 15;
    const int q    = lane >> 4;         // quad 0..3

    __shared__ union {                  // 18432 B
        ushort_t aT[2][64][72];         // [hi/lo][e][k]  (K=64: Orr,Ors,RA,pad)
        float    h2T[64][68];
    } u1;
    __shared__ union {                  // 18432 B
        ushort_t h1T[2][64][72];        // current 64-j half of h1
        float    rs[30][70];            // RS staging (phase A only)
    } u2;
    __shared__ float rrs[30][70];       // 8400 B, persistent (frags + Ebar)
    __shared__ float Ee[64][6];         // 1536 B
    __shared__ float b1s[128], b2s[64]; // 768 B

    if (tid < 128) b1s[tid] = b1[tid];
    if (tid < 64)  b2s[tid] = b2[tid];

    // ---- stage RR -> rrs, RS -> u2.rs (coalesced float2, tail-guarded) ----
    for (int idx = tid; idx < 30 * 32; idx += 256) {
        int n = idx >> 5, g = idx & 31;
        int r = r0 + 2 * g;
        const float* pr = &RR[(b * N_ + n) * NR_];
        const float* ps = &RS[(b * N_ + n) * NR_];
        float v0, v1, s0, s1;
        if (r + 1 < NR_) {
            float2 a = *(const float2*)&pr[r]; v0 = a.x; v1 = a.y;
            float2 c = *(const float2*)&ps[r]; s0 = c.x; s1 = c.y;
        } else {
            int ra_ = r < NR_ ? r : NR_ - 1;
            int rb_ = (r + 1) < NR_ ? (r + 1) : NR_ - 1;
            v0 = pr[ra_]; v1 = pr[rb_]; s0 = ps[ra_]; s1 = ps[rb_];
        }
        rrs[n][2 * g] = v0;  rrs[n][2 * g + 1] = v1;
        u2.rs[n][2 * g] = s0; u2.rs[n][2 * g + 1] = s1;
    }
    __syncthreads();                                      // S1

    // ---- phase A: Orr/Ors via MFMA; wave wv owns e-tile wv ----
    const int eloc = wv * 16 + l15;
    const int r = r0 + eloc;
    const bool rvalid = (r < NR_);

    {
        Frag xh, xl;
        xh.v = ((const short8_t*)xAh)[b * 64 + lane];
        xl.v = ((const short8_t*)xAl)[b * 64 + lane];

        Frag rrh, rrl, rsh, rsl;
        #pragma unroll
        for (int j = 0; j < 8; ++j) {
            int n = q * 8 + j;
            float vr = 0.f, vs = 0.f;
            if (n < N_) { vr = rrs[n][eloc]; vs = u2.rs[n][eloc]; }
            ushort_t h_, l_;
            split(vr, h_, l_); rrh.u[j] = h_; rrl.u[j] = l_;
            split(vs, h_, l_); rsh.u[j] = h_; rsl.u[j] = l_;
        }

        f32x4 aR = {0.f,0.f,0.f,0.f}, aS = {0.f,0.f,0.f,0.f};
        aR = mfma(xh.v, rrh.v, aR); aR = mfma(xl.v, rrh.v, aR); aR = mfma(xh.v, rrl.v, aR);
        aS = mfma(xh.v, rsh.v, aS); aS = mfma(xl.v, rsh.v, aS); aS = mfma(xh.v, rsl.v, aS);

        // zero k=32..63 (8 shorts/lane, wave-local rows; wave-order guarantees
        // the RA scalar overwrite below lands after)
        uint4 z = {0u,0u,0u,0u};
        *(uint4*)&u1.aT[0][eloc][32 + q * 8] = z;
        *(uint4*)&u1.aT[1][eloc][32 + q * 8] = z;

        ushort4 ph, pl; ushort_t h_, l_;
        split(aR[0], h_, l_); ph.x = h_; pl.x = l_;
        split(aR[1], h_, l_); ph.y = h_; pl.y = l_;
        split(aR[2], h_, l_); ph.z = h_; pl.z = l_;
        split(aR[3], h_, l_); ph.w = h_; pl.w = l_;
        *(ushort4*)&u1.aT[0][eloc][q * 4] = ph;
        *(ushort4*)&u1.aT[1][eloc][q * 4] = pl;
        split(aS[0], h_, l_); ph.x = h_; pl.x = l_;
        split(aS[1], h_, l_); ph.y = h_; pl.y = l_;
        split(aS[2], h_, l_); ph.z = h_; pl.z = l_;
        split(aS[3], h_, l_); ph.w = h_; pl.w = l_;
        *(ushort4*)&u1.aT[0][eloc][16 + q * 4] = ph;
        *(ushort4*)&u1.aT[1][eloc][16 + q * 4] = pl;

        if (q < DR_) {
            float v = rvalid ? RA[(b * DR_ + q) * NR_ + r] : 0.f;
            split(v, h_, l_);
            u1.aT[0][eloc][32 + q] = h_;
            u1.aT[1][eloc][32 + q] = l_;
        }
    }
    __syncthreads();                                      // S2 (u2.rs dead)

    // ---- fr1/fr2 halves: fr1 half hf -> h1T; fr2 partial into registers ----
    short8_t W2hf[4], W2lf[4];
    #pragma unroll
    for (int kt = 0; kt < 4; ++kt) {
        W2hf[kt] = ((const short8_t*)w2h)[(wv * 4 + kt) * 64 + lane];
        W2lf[kt] = ((const short8_t*)w2l)[(wv * 4 + kt) * 64 + lane];
    }
    f32x4 acc2[4];
    #pragma unroll
    for (int et = 0; et < 4; ++et) acc2[et] = (f32x4){0.f,0.f,0.f,0.f};

    #pragma unroll
    for (int hf = 0; hf < 2; ++hf) {
        // fr1: wave owns mt = hf*4 + wv  (j1 half-local row = wv*16 + q*4 + c)
        {
            const int mt = hf * 4 + wv;
            short8_t W1hf_[2], W1lf_[2];
            #pragma unroll
            for (int kt = 0; kt < 2; ++kt) {
                W1hf_[kt] = ((const short8_t*)w1h)[(mt * 2 + kt) * 64 + lane];
                W1lf_[kt] = ((const short8_t*)w1l)[(mt * 2 + kt) * 64 + lane];
            }
            #pragma unroll
            for (int et = 0; et < 4; ++et) {
                int e = et * 16 + l15;
                f32x4 acc = {0.f,0.f,0.f,0.f};
                #pragma unroll
                for (int kt = 0; kt < 2; ++kt) {
                    short8_t Bh = *(const short8_t*)&u1.aT[0][e][kt * 32 + q * 8];
                    short8_t Bl = *(const short8_t*)&u1.aT[1][e][kt * 32 + q * 8];
                    acc = mfma(W1hf_[kt], Bh, acc);
                    acc = mfma(W1lf_[kt], Bh, acc);
                    acc = mfma(W1hf_[kt], Bl, acc);
                }
                ushort4 ph, pl; ushort_t h_, l_; float hv;
                hv = fmaxf(acc[0] + b1s[mt * 16 + q * 4 + 0], 0.f); split(hv, h_, l_); ph.x = h_; pl.x = l_;
                hv = fmaxf(acc[1] + b1s[mt * 16 + q * 4 + 1], 0.f); split(hv, h_, l_); ph.y = h_; pl.y = l_;
                hv = fmaxf(acc[2] + b1s[mt * 16 + q * 4 + 2], 0.f); split(hv, h_, l_); ph.z = h_; pl.z = l_;
                hv = fmaxf(acc[3] + b1s[mt * 16 + q * 4 + 3], 0.f); split(hv, h_, l_); ph.w = h_; pl.w = l_;
                *(ushort4*)&u2.h1T[0][e][wv * 16 + q * 4] = ph;
                *(ushort4*)&u2.h1T[1][e][wv * 16 + q * 4] = pl;
            }
        }
        __syncthreads();                                  // S3 / S5

        // fr2 partial: K-tiles kt = hf*2 + {0,1}
        #pragma unroll
        for (int et = 0; et < 4; ++et) {
            int e = et * 16 + l15;
            #pragma unroll
            for (int ktl = 0; ktl < 2; ++ktl) {
                short8_t bh = *(const short8_t*)&u2.h1T[0][e][ktl * 32 + q * 8];
                short8_t bl = *(const short8_t*)&u2.h1T[1][e][ktl * 32 + q * 8];
                acc2[et] = mfma(W2hf[hf * 2 + ktl], bh, acc2[et]);
                acc2[et] = mfma(W2lf[hf * 2 + ktl], bh, acc2[et]);
                acc2[et] = mfma(W2hf[hf * 2 + ktl], bl, acc2[et]);
            }
        }
        if (hf == 1) {
            // epilogue: h2T write (aliases aT; aT dead — last read in fr1 hf=1,
            // which completed before S5)
            #pragma unroll
            for (int et = 0; et < 4; ++et) {
                int e = et * 16 + l15;
                float4 st;
                st.x = fmaxf(acc2[et][0] + b2s[wv * 16 + q * 4 + 0], 0.f);
                st.y = fmaxf(acc2[et][1] + b2s[wv * 16 + q * 4 + 1], 0.f);
                st.z = fmaxf(acc2[et][2] + b2s[wv * 16 + q * 4 + 2], 0.f);
                st.w = fmaxf(acc2[et][3] + b2s[wv * 16 + q * 4 + 3], 0.f);
                *(float4*)&u1.h2T[e][wv * 16 + q * 4] = st;
            }
        }
        __syncthreads();                                  // S4 / S6
    }

    // ---- fr3 (64 -> 5), VALU; w3/b3 from global (L2-hot) ----
    for (int it = tid; it < 64 * DE_; it += 256) {
        int e = it / DE_, i = it - e * DE_;
        float s = b3[i];
        const float* wr = w3 + i * 64;
        #pragma unroll
        for (int k = 0; k < 64; k += 4) {
            float4 hv = *(const float4*)&u1.h2T[e][k];
            float4 wv4 = *(const float4*)&wr[k];
            s += hv.x * wv4.x + hv.y * wv4.y + hv.z * wv4.z + hv.w * wv4.w;
        }
        Ee[e][i] = ((r0 + e) < NR_) ? fmaxf(s, 0.f) : 0.f;
    }
    __syncthreads();                                      // S7

    // ---- Ebar[b][i][n] += sum_e Ee[e][i] * rrs[n][e] ----
    if (tid < DE_ * N_) {
        int i = tid / N_, n = tid - i * N_;
        float s = 0.f;
        #pragma unroll
        for (int e = 0; e < 64; ++e) s += Ee[e][i] * rrs[n][e];
        atomicAdd(&Ebar[(b * DE_ + i) * N_ + n], s);
    }
}

// ---------------------------------------------------------------------------
// k_node: MFMA node MLP. Block = 2 batches, cols = 64 (2 x 32-slot, n<30 valid).
// ---------------------------------------------------------------------------
__global__ __launch_bounds__(256) void k_node(
    const float* __restrict__ x, const float* __restrict__ Ebar,
    const float* __restrict__ bo1, const float* __restrict__ bo2,
    const float* __restrict__ wo3, const float* __restrict__ bo3,
    const ushort_t* __restrict__ wo1h, const ushort_t* __restrict__ wo1l,
    const ushort_t* __restrict__ wo2h, const ushort_t* __restrict__ wo2l,
    float* __restrict__ f180)
{
    const int b0 = blockIdx.x * 2;
    const int tid = threadIdx.x;
    const int lane = tid & 63;
    const int wv = tid >> 6;
    const int l15 = lane & 15;
    const int q = lane >> 4;

    __shared__ ushort_t cT[2][64][40];
    __shared__ ushort_t h1T[2][64][136];
    __shared__ float h2T[64][68];
    __shared__ float b1s[128], b2s[64];

    if (tid < 128) b1s[tid] = bo1[tid];
    if (tid < 64)  b2s[tid] = bo2[tid];

    for (int idx = tid; idx < 64 * 32; idx += 256) {
        int c = idx >> 5, k = idx & 31;
        int bb = c >> 5, n = c & 31;
        float v = 0.f;
        if (n < N_) {
            if (k < 16)      v = x[((b0 + bb) * N_ + n) * P_ + k];
            else if (k < 21) v = Ebar[((b0 + bb) * DE_ + (k - 16)) * N_ + n];
        }
        ushort_t h_, l_; split(v, h_, l_);
        cT[0][c][k] = h_; cT[1][c][k] = l_;
    }
    __syncthreads();

    {
        short8_t Wh[2], Wl[2];
        #pragma unroll
        for (int mi = 0; mi < 2; ++mi) {
            int mt = wv + mi * 4;
            Wh[mi] = ((const short8_t*)wo1h)[mt * 64 + lane];
            Wl[mi] = ((const short8_t*)wo1l)[mt * 64 + lane];
        }
        #pragma unroll
        for (int et = 0; et < 4; ++et) {
            int c = et * 16 + l15;
            short8_t bh = *(const short8_t*)&cT[0][c][q * 8];
            short8_t bl = *(const short8_t*)&cT[1][c][q * 8];
            #pragma unroll
            for (int mi = 0; mi < 2; ++mi) {
                int mt = wv + mi * 4;
                f32x4 acc = {0.f,0.f,0.f,0.f};
                acc = mfma(Wh[mi], bh, acc);
                acc = mfma(Wl[mi], bh, acc);
                acc = mfma(Wh[mi], bl, acc);
                ushort4 ph, pl; ushort_t h_, l_; float hv;
                hv = fmaxf(acc[0] + b1s[mt * 16 + q * 4 + 0], 0.f); split(hv, h_, l_); ph.x = h_; pl.x = l_;
                hv = fmaxf(acc[1] + b1s[mt * 16 + q * 4 + 1], 0.f); split(hv, h_, l_); ph.y = h_; pl.y = l_;
                hv = fmaxf(acc[2] + b1s[mt * 16 + q * 4 + 2], 0.f); split(hv, h_, l_); ph.z = h_; pl.z = l_;
                hv = fmaxf(acc[3] + b1s[mt * 16 + q * 4 + 3], 0.f); split(hv, h_, l_); ph.w = h_; pl.w = l_;
                *(ushort4*)&h1T[0][c][mt * 16 + q * 4] = ph;
                *(ushort4*)&h1T[1][c][mt * 16 + q * 4] = pl;
            }
        }
    }
    __syncthreads();

    {
        short8_t Wh[4], Wl[4];
        #pragma unroll
        for (int kt = 0; kt < 4; ++kt) {
            Wh[kt] = ((const short8_t*)wo2h)[(wv * 4 + kt) * 64 + lane];
            Wl[kt] = ((const short8_t*)wo2l)[(wv * 4 + kt) * 64 + lane];
        }
        #pragma unroll
        for (int et = 0; et < 4; ++et) {
            int c = et * 16 + l15;
            f32x4 acc = {0.f,0.f,0.f,0.f};
            #pragma unroll
            for (int kt = 0; kt < 4; ++kt) {
                short8_t bh = *(const short8_t*)&h1T[0][c][kt * 32 + q * 8];
                short8_t bl = *(const short8_t*)&h1T[1][c][kt * 32 + q * 8];
                acc = mfma(Wh[kt], bh, acc);
                acc = mfma(Wl[kt], bh, acc);
                acc = mfma(Wh[kt], bl, acc);
            }
            float4 st;
            st.x = fmaxf(acc[0] + b2s[wv * 16 + q * 4 + 0], 0.f);
            st.y = fmaxf(acc[1] + b2s[wv * 16 + q * 4 + 1], 0.f);
            st.z = fmaxf(acc[2] + b2s[wv * 16 + q * 4 + 2], 0.f);
            st.w = fmaxf(acc[3] + b2s[wv * 16 + q * 4 + 3], 0.f);
            *(float4*)&h2T[c][wv * 16 + q * 4] = st;
        }
    }
    __syncthreads();

    for (int it = tid; it < 384; it += 256) {
        int c = it / DO_, i = it - c * DO_;
        if (c < 64) {
            int bb = c >> 5, n = c & 31;
            if (n < N_) {
                float s = bo3[i];
                const float* wr = wo3 + i * 64;
                #pragma unroll
                for (int k = 0; k < 64; k += 4) {
                    float4 hv = *(const float4*)&h2T[c][k];
                    float4 wv4 = *(const float4*)&wr[k];
                    s += hv.x * wv4.x + hv.y * wv4.y + hv.z * wv4.z + hv.w * wv4.w;
                }
                f180[(b0 + bb) * 180 + n * DO_ + i] = fmaxf(s, 0.f);
            }
        }
    }
}

// ---------------------------------------------------------------------------
// k_final: fp32 VALU (tiny), 2 batches/block.
// ---------------------------------------------------------------------------
__global__ __launch_bounds__(256) void k_final(
    const float* __restrict__ f180,
    const float* __restrict__ wc1, const float* __restrict__ bc1,
    const float* __restrict__ wc2, const float* __restrict__ bc2,
    const float* __restrict__ wc3, const float* __restrict__ bc3,
    float* __restrict__ out)
{
    const int b0 = blockIdx.x * 2, tid = threadIdx.x;
    __shared__ float fs[2][184];
    __shared__ float h1s[2][128];
    __shared__ float h2s[2][64];

    for (int i = tid; i < 2 * 180; i += 256)
        fs[i / 180][i % 180] = f180[(b0 + i / 180) * 180 + (i % 180)];
    __syncthreads();

    {
        int bl = tid >> 7, j = tid & 127;
        const float* wr = wc1 + j * 180;
        float s = bc1[j];
        #pragma unroll 5
        for (int k = 0; k < 180; k += 4) {
            float4 wv = *(const float4*)&wr[k];
            s += fs[bl][k] * wv.x + fs[bl][k + 1] * wv.y
               + fs[bl][k + 2] * wv.z + fs[bl][k + 3] * wv.w;
        }
        h1s[bl][j] = fmaxf(s, 0.f);
    }
    __syncthreads();

    if (tid < 128) {
        int bl = tid >> 6, j = tid & 63;
        const float* wr = wc2 + j * 128;
        float s = bc2[j];
        #pragma unroll 4
        for (int k = 0; k < 128; k += 4) {
            float4 wv = *(const float4*)&wr[k];
            s += h1s[bl][k] * wv.x + h1s[bl][k + 1] * wv.y
               + h1s[bl][k + 2] * wv.z + h1s[bl][k + 3] * wv.w;
        }
        h2s[bl][j] = fmaxf(s, 0.f);
    }
    __syncthreads();

    if (tid < 10) {
        int bl = tid / 5, t = tid - bl * 5;
        const float* wr = wc3 + t * 64;
        float s = bc3[t];
        #pragma unroll
        for (int k = 0; k < 64; k += 4) {
            float4 wv = *(const float4*)&wr[k];
            s += h2s[bl][k] * wv.x + h2s[bl][k + 1] * wv.y
               + h2s[bl][k + 2] * wv.z + h2s[bl][k + 3] * wv.w;
        }
        out[(b0 + bl) * NT_ + t] = s;
    }
}

extern "C" void kernel_launch(void* const* d_in, const int* in_sizes, int n_in,
                              void* d_out, int out_size, void* d_ws, size_t ws_size,
                              hipStream_t stream)
{
    const float* x    = (const float*)d_in[0];
    const float* RR   = (const float*)d_in[1];
    const float* RS   = (const float*)d_in[2];
    const float* RA   = (const float*)d_in[3];
    const float* fr1w = (const float*)d_in[4];
    const float* fr1b = (const float*)d_in[5];
    const float* fr2w = (const float*)d_in[6];
    const float* fr2b = (const float*)d_in[7];
    const float* fr3w = (const float*)d_in[8];
    const float* fr3b = (const float*)d_in[9];
    const float* fo1w = (const float*)d_in[10];
    const float* fo1b = (const float*)d_in[11];
    const float* fo2w = (const float*)d_in[12];
    const float* fo2b = (const float*)d_in[13];
    const float* fo3w = (const float*)d_in[14];
    const float* fo3b = (const float*)d_in[15];
    const float* fc1w = (const float*)d_in[16];
    const float* fc1b = (const float*)d_in[17];
    const float* fc2w = (const float*)d_in[18];
    const float* fc2b = (const float*)d_in[19];
    const float* fc3w = (const float*)d_in[20];
    const float* fc3b = (const float*)d_in[21];
    float* out = (float*)d_out;

    // ---- workspace map ----
    float* Ebar = (float*)d_ws;                       // 1024*5*30
    float* f180 = Ebar + B_ * DE_ * N_;               // 1024*180
    ushort_t* base = (ushort_t*)(f180 + B_ * 180);
    ushort_t* xAh  = base;             ushort_t* xAl  = xAh  + 1024 * 512;
    ushort_t* w1h  = xAl  + 1024*512;  ushort_t* w1l  = w1h  + 16 * 512;
    ushort_t* w2h  = w1l  + 16*512;    ushort_t* w2l  = w2h  + 16 * 512;
    ushort_t* wo1h = w2l  + 16*512;    ushort_t* wo1l = wo1h + 8 * 512;
    ushort_t* wo2h = wo1l + 8*512;     ushort_t* wo2l = wo2h + 16 * 512;

    hipMemsetAsync(Ebar, 0, (size_t)B_ * DE_ * N_ * sizeof(float), stream);

    k_prep<<<1028, 256, 0, stream>>>(x, fr1w, fr2w, fo1w, fo2w,
                                     xAh, xAl, w1h, w1l, w2h, w2l,
                                     wo1h, wo1l, wo2h, wo2l);

    dim3 g1(14, B_);   // 14 * 64 = 896 >= 870 edges
    k_edge<<<g1, 256, 0, stream>>>(RR, RS, RA, fr1b, fr2b, fr3w, fr3b,
                                   xAh, xAl, w1h, w1l, w2h, w2l, Ebar);
    k_node<<<B_ / 2, 256, 0, stream>>>(x, Ebar, fo1b, fo2b, fo3w, fo3b,
                                       wo1h, wo1l, wo2h, wo2l, f180);
    k_final<<<B_ / 2, 256, 0, stream>>>(f180, fc1w, fc1b, fc2w, fc2b,
                                        fc3w, fc3b, out);
}